// Round 6
// baseline (2771.182 us; speedup 1.0000x reference)
//
#include <hip/hip_runtime.h>

#define L_PAD 8192
#define HS    25
#define ES    50
#define G4    100   // 4*H
#define LOG2E 1.44269504088896340736f

typedef float v2f __attribute__((ext_vector_type(2)));
typedef float v4f __attribute__((ext_vector_type(4)));

// -------- workspace layout --------
// zs2   : float2[2][L_PAD*50]   packed gate preacts: zs2[d][t*50+j] = (z[j], z[j+50])
// wstar : float2[2][50]         h* @ Wh, same packing
// cstar : float [2][25]         frozen cell state

__device__ __forceinline__ float rl_f(float v, int lane) {
    return __int_as_float(__builtin_amdgcn_readlane(__float_as_int(v), lane));
}
__device__ __forceinline__ float fast_sigmoid(float x) {
    return __builtin_amdgcn_rcpf(1.f + __builtin_amdgcn_exp2f(x * (-LOG2E)));
}
__device__ __forceinline__ float fast_tanh(float x) {
    // 2*sigmoid(2x) - 1
    return fmaf(__builtin_amdgcn_rcpf(1.f + __builtin_amdgcn_exp2f(x * (-2.f * LOG2E))), 2.f, -1.f);
}

// ---------------- kernel 1: pre-activations (parallel) ----------------
__global__ __launch_bounds__(64) void k_pre(
    const int* __restrict__ tok, const int* __restrict__ plen,
    const float* __restrict__ Ef, const float* __restrict__ Wif, const float* __restrict__ bf,
    const float* __restrict__ Eb, const float* __restrict__ Wib, const float* __restrict__ bb,
    float2* __restrict__ zs2)
{
    const int b = blockIdx.x;
    const int d = b & 1;
    const int t = b >> 1;
    const int j = threadIdx.x;
    const int len = *plen;

    int src;
    if (d == 0) src = t;
    else        src = (t < len) ? (len - 1 - t) : (L_PAD - 1 - (t - len));
    const int token = tok[src];

    const float* __restrict__ E  = d ? Eb  : Ef;
    const float* __restrict__ Wi = d ? Wib : Wif;
    const float* __restrict__ bs = d ? bb  : bf;

    __shared__ float e[ES];
    if (j < ES) e[j] = E[(size_t)token * ES + j];
    __syncthreads();
    if (j >= 50) return;

    float ax = bs[j], ay = bs[j + 50];
    float bx = 0.f,  by = 0.f;
    #pragma unroll
    for (int k = 0; k < ES; k += 2) {
        float e0 = e[k], e1 = e[k + 1];
        ax = fmaf(e0, Wi[k * G4 + j],            ax);
        ay = fmaf(e0, Wi[k * G4 + j + 50],       ay);
        bx = fmaf(e1, Wi[(k + 1) * G4 + j],      bx);
        by = fmaf(e1, Wi[(k + 1) * G4 + j + 50], by);
    }
    zs2[(size_t)d * (L_PAD * 50) + t * 50 + j] = make_float2(ax + bx, ay + by);
}

// ---------------- kernel 2: the serial recurrence (latency-bound) ----------------
// one wave per direction. lane j in [0,50): gates (j, j+50).
//   lanes 0..24 -> (i_k, g_k),  lanes 25..49 -> (f_k, o_k)
// Rounds 1-5: every attempt to keep the 50 loop-invariant Wh values in VGPRs
// (launch_bounds, asm pins, waves_per_eu) gave VGPR_Count=36-40 and identical
// time -> RA spills W to scratch; per-step buffer_load reloads sit in the
// vmcnt domain ON the serial chain and also drain the z-prefetch (waitcnt
// vmcnt(N) waits oldest-first). Fix: W lives in LDS (lgkmcnt domain, no RA
// discretion). LICM of the loop-invariant LDS reads (which would recreate the
// spill) is defeated by pinning the LDS index with an opaque asm every
// iteration. FMAs packed as v_pk_fma_f32 via 2-wide vector math.
__global__ __launch_bounds__(64, 1)
__attribute__((amdgpu_waves_per_eu(1, 1)))
void k_seq(
    const float* __restrict__ Whf, const float* __restrict__ Whb,
    const int* __restrict__ plen,
    const float2* __restrict__ zs2_all,
    float* __restrict__ out,
    float2* __restrict__ wstar, float* __restrict__ cstar)
{
    const int d = blockIdx.x;
    const int j = threadIdx.x;
    const int len = *plen;
    const float* __restrict__ Wh = d ? Whb : Whf;
    const v2f* __restrict__ z = (const v2f*)zs2_all + (size_t)d * (L_PAD * 50);
    const int jj = (j < 50) ? j : 0;

    // LDS weight bank: WP[p][q] = (wx[2p], wy[2p], wx[2p+1], wy[2p+1]) for col q
    __shared__ v4f WP[12][50];   // k = 0..23, 9600 B
    __shared__ v2f W24[50];      // k = 24,      400 B
    for (int idx = j; idx < 600; idx += 64) {
        int p = idx / 50, q = idx - p * 50, k = 2 * p;
        WP[p][q] = (v4f){ Wh[k * G4 + q],       Wh[k * G4 + q + 50],
                          Wh[(k + 1) * G4 + q], Wh[(k + 1) * G4 + q + 50] };
    }
    if (j < 50) W24[j] = (v2f){ Wh[24 * G4 + j], Wh[24 * G4 + j + 50] };
    __syncthreads();

    // branch-free activation constants: second gate is tanh for lanes<25, sigmoid otherwise
    const bool  isG = (j < 25);
    const float my = isG ? (-2.f * LOG2E) : (-LOG2E);
    const float ca = isG ? 2.f : 1.f;
    const float cb = isG ? -1.f : 0.f;

    float c = 0.f, h = 0.f;   // lanes 0..24 carry real state; other lanes' values never read
    const v2f* __restrict__ zb = z + jj;
    // register prefetch pipeline, distance 6 (vmcnt domain now holds ONLY these + the store)
    v2f zq0 = zb[0],   zq1 = zb[50],  zq2 = zb[100];
    v2f zq3 = zb[150], zq4 = zb[200], zq5 = zb[250];
    float* outp = out + d * HS + j;   // stride 50 floats per step

#define PAIR(p, cA, cB) { v4f w = WP[p][oj];                              \
        float hA = rl_f(h, 2 * (p)); float hB = rl_f(h, 2 * (p) + 1);     \
        v2f wlo = {w.x, w.y}, whi = {w.z, w.w};                           \
        cA += wlo * (v2f){hA, hA};                                        \
        cB += whi * (v2f){hB, hB}; }

    for (int t = 0; t < len; ++t) {
        int tp = t + 6; tp = (tp < L_PAD) ? tp : (L_PAD - 1);
        v2f zf = zb[tp * 50];

        int oj = jj;
        asm volatile("" : "+v"(oj));   // opaque index: blocks LICM/CSE of the LDS reads

        v2f a0 = zq0;
        v2f a1 = {0.f, 0.f}, a2 = {0.f, 0.f}, a3 = {0.f, 0.f};
        PAIR(0, a0, a1)  PAIR(1, a2, a3)  PAIR(2, a0, a1)  PAIR(3, a2, a3)
        PAIR(4, a0, a1)  PAIR(5, a2, a3)  PAIR(6, a0, a1)  PAIR(7, a2, a3)
        PAIR(8, a0, a1)  PAIR(9, a2, a3)  PAIR(10, a0, a1) PAIR(11, a2, a3)
        { v2f w = W24[oj]; float hk = rl_f(h, 24); a0 += w * (v2f){hk, hk}; }
        v2f pp = (a0 + a1) + (a2 + a3);

        float sa = fast_sigmoid(pp.x);                   // i (lanes<25) / f (lanes>=25)
        float ry = __builtin_amdgcn_rcpf(1.f + __builtin_amdgcn_exp2f(pp.y * my));
        float sb = fmaf(ry, ca, cb);                     // g=tanh (lanes<25) / o=sigmoid

        float f_ = __shfl(sa, j + 25);                   // lane k reads lane k+25
        float o_ = __shfl(sb, j + 25);
        float nc = fmaf(f_, c, sa * sb);                 // f*c + i*g
        float nh = o_ * fast_tanh(nc);
        c = nc;                                          // unconditional: upper-lane
        h = nh;                                          //  garbage is never readlane'd
        if (j < 25) outp[t * 50] = nh;                   // out[t*50 + d*25 + j]
        zq0 = zq1; zq1 = zq2; zq2 = zq3; zq3 = zq4; zq4 = zq5; zq5 = zf;
    }
#undef PAIR

    // epilogue: w* = h* @ Wh (packed) and c* for the frozen tail
    v2f e = {0.f, 0.f};
    #pragma unroll
    for (int p = 0; p < 12; ++p) {
        v4f w = WP[p][jj];
        float hA = rl_f(h, 2 * p), hB = rl_f(h, 2 * p + 1);
        e += (v2f){w.x, w.y} * (v2f){hA, hA};
        e += (v2f){w.z, w.w} * (v2f){hB, hB};
    }
    { v2f w = W24[jj]; float hk = rl_f(h, 24); e += w * (v2f){hk, hk}; }
    if (j < 50) wstar[d * 50 + j] = make_float2(e.x, e.y);
    if (j < 25) cstar[d * HS + j] = c;
}

// ---------------- kernel 3: frozen-carry tail (parallel) ----------------
__global__ __launch_bounds__(256) void k_tail(
    const int* __restrict__ plen,
    const float2* __restrict__ zs2_all,
    const float2* __restrict__ wstar, const float* __restrict__ cstar,
    float* __restrict__ out)
{
    const int tid = blockIdx.x * 256 + threadIdx.x;
    if (tid >= L_PAD * 50) return;
    const int col = tid % 50;
    const int t   = tid / 50;
    const int len = *plen;
    if (t < len) return;
    const int d = col / HS;
    const int j = col % HS;

    const float2* __restrict__ z = zs2_all + (size_t)d * (L_PAD * 50);
    float2 zi = z[t * 50 + j];
    float2 zq = z[t * 50 + j + 25];
    float2 wi = wstar[d * 50 + j];
    float2 wq = wstar[d * 50 + j + 25];

    float i_ = fast_sigmoid(zi.x + wi.x);
    float g_ = fast_tanh  (zi.y + wi.y);
    float f_ = fast_sigmoid(zq.x + wq.x);
    float o_ = fast_sigmoid(zq.y + wq.y);

    float nc = fmaf(f_, cstar[d * HS + j], i_ * g_);
    out[t * 50 + col] = o_ * fast_tanh(nc);
}

extern "C" void kernel_launch(void* const* d_in, const int* in_sizes, int n_in,
                              void* d_out, int out_size, void* d_ws, size_t ws_size,
                              hipStream_t stream)
{
    const int*   tok  = (const int*)  d_in[0];
    const int*   plen = (const int*)  d_in[1];
    const float* Ef   = (const float*)d_in[2];
    const float* Wif  = (const float*)d_in[3];
    const float* Whf  = (const float*)d_in[4];
    const float* bf   = (const float*)d_in[5];
    const float* Eb   = (const float*)d_in[6];
    const float* Wib  = (const float*)d_in[7];
    const float* Whb  = (const float*)d_in[8];
    const float* bb   = (const float*)d_in[9];
    float* out = (float*)d_out;

    float2* zs2   = (float2*)d_ws;
    float2* wstar = (float2*)((char*)d_ws + (size_t)2 * L_PAD * 50 * sizeof(float2));
    float*  cstar = (float*)((char*)wstar + 100 * sizeof(float2));

    k_pre <<<2 * L_PAD, 64, 0, stream>>>(tok, plen, Ef, Wif, bf, Eb, Wib, bb, zs2);
    k_seq <<<2, 64, 0, stream>>>(Whf, Whb, plen, zs2, out, wstar, cstar);
    k_tail<<<(L_PAD * 50 + 255) / 256, 256, 0, stream>>>(plen, zs2, wstar, cstar, out);
}

// Round 8
// 2291.022 us; speedup vs baseline: 1.2096x; 1.2096x over previous
//
#include <hip/hip_runtime.h>

#define L_PAD 8192
#define HS    25
#define ES    50
#define G4    100   // 4*H
#define LOG2E 1.44269504088896340736f

typedef float v2f __attribute__((ext_vector_type(2)));
// match the exact vector-of-fp16 type the builtins use (clang 'V2h'):
using v2h = decltype(__builtin_amdgcn_cvt_pkrtz(0.f, 0.f));

// -------- workspace layout --------
// zs2   : float2[2][L_PAD*50]   packed gate preacts: zs2[d][t*50+j] = (z[j], z[j+50])
// wstar : float2[2][50]         h* @ Wh, same packing
// cstar : float [2][25]         frozen cell state

__device__ __forceinline__ float rl_f(float v, int lane) {
    return __int_as_float(__builtin_amdgcn_readlane(__float_as_int(v), lane));
}
__device__ __forceinline__ float fast_sigmoid(float x) {
    return __builtin_amdgcn_rcpf(1.f + __builtin_amdgcn_exp2f(x * (-LOG2E)));
}
__device__ __forceinline__ float fast_tanh(float x) {
    // 2*sigmoid(2x) - 1
    return fmaf(__builtin_amdgcn_rcpf(1.f + __builtin_amdgcn_exp2f(x * (-2.f * LOG2E))), 2.f, -1.f);
}

#if __has_builtin(__builtin_amdgcn_fdot2)
#define FDOT2(a, b, c) __builtin_amdgcn_fdot2((a), (b), (c), false)
#else
#define FDOT2(a, b, c) fmaf((float)(a).x, (float)(b).x, fmaf((float)(a).y, (float)(b).y, (c)))
#endif

// ---------------- kernel 1: pre-activations (parallel) ----------------
__global__ __launch_bounds__(64) void k_pre(
    const int* __restrict__ tok, const int* __restrict__ plen,
    const float* __restrict__ Ef, const float* __restrict__ Wif, const float* __restrict__ bf,
    const float* __restrict__ Eb, const float* __restrict__ Wib, const float* __restrict__ bb,
    float2* __restrict__ zs2)
{
    const int b = blockIdx.x;
    const int d = b & 1;
    const int t = b >> 1;
    const int j = threadIdx.x;
    const int len = *plen;

    int src;
    if (d == 0) src = t;
    else        src = (t < len) ? (len - 1 - t) : (L_PAD - 1 - (t - len));
    const int token = tok[src];

    const float* __restrict__ E  = d ? Eb  : Ef;
    const float* __restrict__ Wi = d ? Wib : Wif;
    const float* __restrict__ bs = d ? bb  : bf;

    __shared__ float e[ES];
    if (j < ES) e[j] = E[(size_t)token * ES + j];
    __syncthreads();
    if (j >= 50) return;

    float ax = bs[j], ay = bs[j + 50];
    float bx = 0.f,  by = 0.f;
    #pragma unroll
    for (int k = 0; k < ES; k += 2) {
        float e0 = e[k], e1 = e[k + 1];
        ax = fmaf(e0, Wi[k * G4 + j],            ax);
        ay = fmaf(e0, Wi[k * G4 + j + 50],       ay);
        bx = fmaf(e1, Wi[(k + 1) * G4 + j],      bx);
        by = fmaf(e1, Wi[(k + 1) * G4 + j + 50], by);
    }
    zs2[(size_t)d * (L_PAD * 50) + t * 50 + j] = make_float2(ax + bx, ay + by);
}

// ---------------- kernel 2: the serial recurrence (latency-bound) ----------------
// one wave per direction. lane j in [0,50): gates (j, j+50).
//   lanes 0..24 -> (i_k, g_k),  lanes 25..49 -> (f_k, o_k)
// Rounds 1-6 evidence: 50 f32 weights/lane never stay resident (RA behaves as
// if capped at ~64 VGPRs: spills with pins, waves_per_eu ignored) and LDS
// residency is slower (serialized ds_read latency + conflicts). Fix: pack the
// weights as f16 PAIRS -> 26 VGPRs for all 50 weights; per step
// 13 x (2 readlane + v_cvt_pkrtz + 2 v_dot2_f32_f16). Whole working set
// ~58 VGPRs: fits the budget honestly -> the loop touches NO memory except
// the z-prefetch stream and the output store.
__global__ __launch_bounds__(64, 1)
__attribute__((amdgpu_waves_per_eu(1, 1)))
void k_seq(
    const float* __restrict__ Whf, const float* __restrict__ Whb,
    const int* __restrict__ plen,
    const float2* __restrict__ zs2_all,
    float* __restrict__ out,
    float2* __restrict__ wstar, float* __restrict__ cstar)
{
    const int d = blockIdx.x;
    const int j = threadIdx.x;
    const int len = *plen;
    const float* __restrict__ Wh = d ? Whb : Whf;
    const v2f* __restrict__ z = (const v2f*)zs2_all + (size_t)d * (L_PAD * 50);
    const int jj = (j < 50) ? j : 0;

    // 26 packed-f16 weight registers: wx{p}=(Wx[2p],Wx[2p+1]), wy{p}=(Wy[2p],Wy[2p+1])
    // pair p=12 pads slot 25 with 0 -> its dot2 contribution is exactly 0.
#define LW2(p, k0, k1) \
    v2h wx##p = __builtin_amdgcn_cvt_pkrtz(Wh[(k0)*G4 + jj], \
                                           (k1) < HS ? Wh[(k1)*G4 + jj] : 0.f); \
    v2h wy##p = __builtin_amdgcn_cvt_pkrtz(Wh[(k0)*G4 + jj + 50], \
                                           (k1) < HS ? Wh[(k1)*G4 + jj + 50] : 0.f);
    LW2(0,  0,  1)  LW2(1,  2,  3)  LW2(2,  4,  5)  LW2(3,  6,  7)
    LW2(4,  8,  9)  LW2(5, 10, 11)  LW2(6, 12, 13)  LW2(7, 14, 15)
    LW2(8, 16, 17)  LW2(9, 18, 19)  LW2(10, 20, 21) LW2(11, 22, 23)
    LW2(12, 24, 25)
#undef LW2

    // branch-free activation constants: second gate is tanh for lanes<25, sigmoid otherwise
    const bool  isG = (j < 25);
    const float my = isG ? (-2.f * LOG2E) : (-LOG2E);
    const float ca = isG ? 2.f : 1.f;
    const float cb = isG ? -1.f : 0.f;

    float c = 0.f, h = 0.f;   // lanes 0..24 carry real state; other lanes' values never read
    const v2f* __restrict__ zb = z + jj;
    // register prefetch pipeline, distance 6 (vmcnt domain holds ONLY these + the store)
    v2f zq0 = zb[0],   zq1 = zb[50],  zq2 = zb[100];
    v2f zq3 = zb[150], zq4 = zb[200], zq5 = zb[250];
    float* outp = out + d * HS + j;   // stride 50 floats per step

    // readlane lane indices are compile-time constants; slot 25 reads lane 25
    // (finite garbage) but multiplies the zero pad weight.
#define DOT(p, k0, k1, A) { \
        float hA = rl_f(h, k0); \
        float hB = rl_f(h, (k1) < HS ? (k1) : HS); \
        v2h hp = __builtin_amdgcn_cvt_pkrtz(hA, hB); \
        ax##A = FDOT2(wx##p, hp, ax##A); \
        ay##A = FDOT2(wy##p, hp, ay##A); }

    for (int t = 0; t < len; ++t) {
        int tp = t + 6; tp = (tp < L_PAD) ? tp : (L_PAD - 1);
        v2f zf = zb[tp * 50];

        // z + h @ Wh : 2x2 accumulator chains, depth ceil(13/2)=7 dot2
        float ax0 = zq0.x, ay0 = zq0.y;
        float ax1 = 0.f,   ay1 = 0.f;
        DOT(0,  0,  1, 0)  DOT(1,  2,  3, 1)
        DOT(2,  4,  5, 0)  DOT(3,  6,  7, 1)
        DOT(4,  8,  9, 0)  DOT(5, 10, 11, 1)
        DOT(6, 12, 13, 0)  DOT(7, 14, 15, 1)
        DOT(8, 16, 17, 0)  DOT(9, 18, 19, 1)
        DOT(10, 20, 21, 0) DOT(11, 22, 23, 1)
        DOT(12, 24, 25, 0)
        float px = ax0 + ax1;
        float py = ay0 + ay1;

        float sa = fast_sigmoid(px);                     // i (lanes<25) / f (lanes>=25)
        float ry = __builtin_amdgcn_rcpf(1.f + __builtin_amdgcn_exp2f(py * my));
        float sb = fmaf(ry, ca, cb);                     // g=tanh (lanes<25) / o=sigmoid

        float f_ = __shfl(sa, j + 25);                   // lane k reads lane k+25
        float o_ = __shfl(sb, j + 25);
        float nc = fmaf(f_, c, sa * sb);                 // f*c + i*g
        float nh = o_ * fast_tanh(nc);
        c = nc;                                          // unconditional: upper-lane
        h = nh;                                          //  garbage is never readlane'd
        if (j < 25) outp[t * 50] = nh;                   // out[t*50 + d*25 + j]
        zq0 = zq1; zq1 = zq2; zq2 = zq3; zq3 = zq4; zq4 = zq5; zq5 = zf;
    }

    // epilogue: w* = h* @ Wh (same f16 weights as the loop) and c* for the tail
    float ax0 = 0.f, ay0 = 0.f, ax1 = 0.f, ay1 = 0.f;
    DOT(0,  0,  1, 0)  DOT(1,  2,  3, 1)
    DOT(2,  4,  5, 0)  DOT(3,  6,  7, 1)
    DOT(4,  8,  9, 0)  DOT(5, 10, 11, 1)
    DOT(6, 12, 13, 0)  DOT(7, 14, 15, 1)
    DOT(8, 16, 17, 0)  DOT(9, 18, 19, 1)
    DOT(10, 20, 21, 0) DOT(11, 22, 23, 1)
    DOT(12, 24, 25, 0)
#undef DOT
    if (j < 50) wstar[d * 50 + j] = make_float2(ax0 + ax1, ay0 + ay1);
    if (j < 25) cstar[d * HS + j] = c;
}

// ---------------- kernel 3: frozen-carry tail (parallel) ----------------
__global__ __launch_bounds__(256) void k_tail(
    const int* __restrict__ plen,
    const float2* __restrict__ zs2_all,
    const float2* __restrict__ wstar, const float* __restrict__ cstar,
    float* __restrict__ out)
{
    const int tid = blockIdx.x * 256 + threadIdx.x;
    if (tid >= L_PAD * 50) return;
    const int col = tid % 50;
    const int t   = tid / 50;
    const int len = *plen;
    if (t < len) return;
    const int d = col / HS;
    const int j = col % HS;

    const float2* __restrict__ z = zs2_all + (size_t)d * (L_PAD * 50);
    float2 zi = z[t * 50 + j];
    float2 zq = z[t * 50 + j + 25];
    float2 wi = wstar[d * 50 + j];
    float2 wq = wstar[d * 50 + j + 25];

    float i_ = fast_sigmoid(zi.x + wi.x);
    float g_ = fast_tanh  (zi.y + wi.y);
    float f_ = fast_sigmoid(zq.x + wq.x);
    float o_ = fast_sigmoid(zq.y + wq.y);

    float nc = fmaf(f_, cstar[d * HS + j], i_ * g_);
    out[t * 50 + col] = o_ * fast_tanh(nc);
}

extern "C" void kernel_launch(void* const* d_in, const int* in_sizes, int n_in,
                              void* d_out, int out_size, void* d_ws, size_t ws_size,
                              hipStream_t stream)
{
    const int*   tok  = (const int*)  d_in[0];
    const int*   plen = (const int*)  d_in[1];
    const float* Ef   = (const float*)d_in[2];
    const float* Wif  = (const float*)d_in[3];
    const float* Whf  = (const float*)d_in[4];
    const float* bf   = (const float*)d_in[5];
    const float* Eb   = (const float*)d_in[6];
    const float* Wib  = (const float*)d_in[7];
    const float* Whb  = (const float*)d_in[8];
    const float* bb   = (const float*)d_in[9];
    float* out = (float*)d_out;

    float2* zs2   = (float2*)d_ws;
    float2* wstar = (float2*)((char*)d_ws + (size_t)2 * L_PAD * 50 * sizeof(float2));
    float*  cstar = (float*)((char*)wstar + 100 * sizeof(float2));

    k_pre <<<2 * L_PAD, 64, 0, stream>>>(tok, plen, Ef, Wif, bf, Eb, Wib, bb, zs2);
    k_seq <<<2, 64, 0, stream>>>(Whf, Whb, plen, zs2, out, wstar, cstar);
    k_tail<<<(L_PAD * 50 + 255) / 256, 256, 0, stream>>>(plen, zs2, wstar, cstar, out);
}